// Round 12
// baseline (123.075 us; speedup 1.0000x reference)
//
#include <hip/hip_runtime.h>
#include <math.h>

// BaseHybridHead, 3 stream-ordered kernels (R11 structure; KB re-tiled):
//  KA: pre-GEMM + rank-1 expand -> psi0 (8192x1024 f16); Arm rows (1024x1024);
//      zero z[8192][10].                       [R7/R11-verified, 2048 blocks]
//  KB: MFMA GEMM psif = psi0 @ Arm^T, 64x128 (MxN) tile, BK=128, XOR-swizzled
//      LDS, classic 2-barrier staged K-loop (only 8 staging rounds), 48KB LDS
//      -> 3 blocks/CU resident for barrier-drain overlap. Fused +-square
//      measurement epilogue -> LDS combine -> atomicAdd z.  [R6 mapping]
//  KC: out = z @ Wpost^T + bpost.              [R6-verified]

#define NQ   10
#define NREG 16
#define DIM  1024

typedef _Float16 f16;
typedef _Float16 f16x8 __attribute__((ext_vector_type(8)));
typedef float    f32x4 __attribute__((ext_vector_type(4)));

// ---------------------------------------------------------------- gate ops
template<int BB>
__device__ __forceinline__ void ry_lane(float (&s)[NREG], int lane, float c, float si) {
    float sgn = ((lane >> BB) & 1) ? si : -si;
    #pragma unroll
    for (int r = 0; r < NREG; ++r) {
        float o = __shfl_xor(s[r], 1 << BB);
        s[r] = fmaf(sgn, o, c * s[r]);
    }
}
template<int P>
__device__ __forceinline__ void ry_reg(float (&s)[NREG], float c, float si) {
    const int m = 1 << P;
    #pragma unroll
    for (int r = 0; r < NREG; ++r) {
        if ((r & m) == 0) {
            float a = s[r], b = s[r + m];
            s[r]     = fmaf(c, a, -si * b);
            s[r + m] = fmaf(si, a,  c * b);
        }
    }
}
__device__ __forceinline__ void cnot_5_6(float (&s)[NREG], int lane) {
    bool sel = (lane & 1) != 0;
    #pragma unroll
    for (int r = 0; r < 8; ++r) {
        float a = s[r], b = s[r + 8];
        s[r]     = sel ? b : a;
        s[r + 8] = sel ? a : b;
    }
}
template<int PC, int PT>
__device__ __forceinline__ void cnot_reg(float (&s)[NREG]) {
    #pragma unroll
    for (int r = 0; r < NREG; ++r) {
        if (((r >> PC) & 1) && !((r >> PT) & 1)) {
            float t = s[r];
            s[r] = s[r ^ (1 << PT)];
            s[r ^ (1 << PT)] = t;
        }
    }
}
__device__ __forceinline__ void perm_even(float (&s)[NREG], int lane) {
    int src = lane ^ (((((lane >> 5) & 1) << 4)) | ((((lane >> 3) & 1) << 2)) | (((lane >> 1) & 1)));
    #pragma unroll
    for (int r = 0; r < NREG; ++r) s[r] = __shfl(s[r], src);
}
__device__ __forceinline__ void perm_odd(float (&s)[NREG], int lane) {
    int src = lane ^ (((((lane >> 4) & 1) << 3)) | ((((lane >> 2) & 1) << 1)));
    #pragma unroll
    for (int r = 0; r < NREG; ++r) s[r] = __shfl(s[r], src);
}

#define APPLY_RY_ALL(CARR, SARR, BASE)                                        \
    { float c_, s_;                                                           \
      c_=__shfl(CARR,(BASE)+0); s_=__shfl(SARR,(BASE)+0); ry_lane<5>(s,lane,c_,s_); \
      c_=__shfl(CARR,(BASE)+1); s_=__shfl(SARR,(BASE)+1); ry_lane<4>(s,lane,c_,s_); \
      c_=__shfl(CARR,(BASE)+2); s_=__shfl(SARR,(BASE)+2); ry_lane<3>(s,lane,c_,s_); \
      c_=__shfl(CARR,(BASE)+3); s_=__shfl(SARR,(BASE)+3); ry_lane<2>(s,lane,c_,s_); \
      c_=__shfl(CARR,(BASE)+4); s_=__shfl(SARR,(BASE)+4); ry_lane<1>(s,lane,c_,s_); \
      c_=__shfl(CARR,(BASE)+5); s_=__shfl(SARR,(BASE)+5); ry_lane<0>(s,lane,c_,s_); \
      c_=__shfl(CARR,(BASE)+6); s_=__shfl(SARR,(BASE)+6); ry_reg<3>(s,c_,s_);       \
      c_=__shfl(CARR,(BASE)+7); s_=__shfl(SARR,(BASE)+7); ry_reg<2>(s,c_,s_);       \
      c_=__shfl(CARR,(BASE)+8); s_=__shfl(SARR,(BASE)+8); ry_reg<1>(s,c_,s_);       \
      c_=__shfl(CARR,(BASE)+9); s_=__shfl(SARR,(BASE)+9); ry_reg<0>(s,c_,s_); }

__device__ __forceinline__ void async16(const void* g, void* l) {
    __builtin_amdgcn_global_load_lds(
        (const __attribute__((address_space(1))) void*)g,
        (__attribute__((address_space(3))) void*)l, 16, 0, 0);
}

// ---------------------------------------------------------------- KA  [R11-verified]
__global__ __launch_bounds__(256) void ka_prepare(
    const float* __restrict__ X, const float* __restrict__ Wpre,
    const float* __restrict__ bpre, const float* __restrict__ qp,
    f16* __restrict__ psi0, f16* __restrict__ Arm, float* __restrict__ z, int B)
{
    const int tid = threadIdx.x, lane = tid & 63, wv = tid >> 6;

    {
        int idx = blockIdx.x * 256 + tid;
        if (idx < 8192 * NQ) z[idx] = 0.0f;
    }

    {
        int sample = blockIdx.x * 4 + wv;
        if (sample < B) {
            const float* xrow = X + (size_t)sample * 512;
            float4 x0 = ((const float4*)xrow)[lane];
            float4 x1 = ((const float4*)xrow)[64 + lane];
            float acc[NQ];
            #pragma unroll
            for (int q = 0; q < NQ; ++q) {
                const float* wr = Wpre + q * 512;
                float4 w0 = ((const float4*)wr)[lane];
                float4 w1 = ((const float4*)wr)[64 + lane];
                float a = x0.x * w0.x;
                a = fmaf(x0.y, w0.y, a); a = fmaf(x0.z, w0.z, a); a = fmaf(x0.w, w0.w, a);
                a = fmaf(x1.x, w1.x, a); a = fmaf(x1.y, w1.y, a);
                a = fmaf(x1.z, w1.z, a); a = fmaf(x1.w, w1.w, a);
                acc[q] = a;
            }
            #pragma unroll
            for (int q = 0; q < NQ; ++q) {
                float v = acc[q];
                #pragma unroll
                for (int d = 32; d >= 1; d >>= 1) v += __shfl_xor(v, d);
                acc[q] = v;
            }
            float pre = acc[0];
            #pragma unroll
            for (int q = 1; q < NQ; ++q) pre = (lane == q) ? acc[q] : pre;
            float c45 = 0.0f, s45 = 0.0f;
            if (lane < NQ) {
                float th = tanhf(pre + bpre[lane]) * 1.5707963267948966f;
                sincosf(0.5f * th + 0.7853981633974483f, &s45, &c45);
            }
            float lv = 1.0f;
            #pragma unroll
            for (int w = 0; w < 6; ++w) {
                float f0 = __shfl(c45, w), f1 = __shfl(s45, w);
                lv *= ((lane >> (5 - w)) & 1) ? f1 : f0;
            }
            float c6 = __shfl(c45, 6), s6 = __shfl(s45, 6);
            float c7 = __shfl(c45, 7), s7 = __shfl(s45, 7);
            float c8 = __shfl(c45, 8), s8 = __shfl(s45, 8);
            float c9 = __shfl(c45, 9), s9 = __shfl(s45, 9);
            float g01[4] = {c6 * c7, c6 * s7, s6 * c7, s6 * s7};
            float g23[4] = {c8 * c9, c8 * s9, s8 * c9, s8 * s9};
            union { f16 h[16]; float4 v[2]; } u;
            #pragma unroll
            for (int r = 0; r < NREG; ++r)
                u.h[r] = (f16)(lv * g01[r >> 2] * g23[r & 3]);
            float4* dst = (float4*)((char*)psi0 + (size_t)sample * 2048 + lane * 32);
            dst[0] = u.v[0];
            dst[1] = u.v[1];
        }
    }

    if (wv < 2) {
        int row = blockIdx.x * 2 + wv;
        if (row < DIM) {
            float cw = 1.0f, swn = 0.0f;
            if (lane < 60) {
                float s_, c_;
                sincosf(0.5f * qp[10 + lane], &s_, &c_);
                cw = c_; swn = -s_;
            }
            float s[NREG];
            int srcLane = row >> 4, srcReg = row & 15;
            #pragma unroll
            for (int r = 0; r < NREG; ++r)
                s[r] = (lane == srcLane && r == srcReg) ? 1.0f : 0.0f;
            for (int kk = 6; kk >= 1; --kk) {
                APPLY_RY_ALL(cw, swn, (kk - 1) * 10);
                perm_odd(s, lane);
                cnot_5_6(s, lane);
                cnot_reg<2, 1>(s);
                perm_even(s, lane);
                cnot_reg<3, 2>(s);
                cnot_reg<1, 0>(s);
            }
            union { f16 h[16]; float4 v[2]; } u;
            #pragma unroll
            for (int r = 0; r < NREG; ++r) u.h[r] = (f16)s[r];
            float4* dst = (float4*)((char*)Arm + (size_t)row * 2048 + lane * 32);
            dst[0] = u.v[0];
            dst[1] = u.v[1];
        }
    }
}

// ---------------------------------------------------------------- KB
// 64x128 (MxN) tile, BK=128, 1024 blocks (mB=blockIdx&127, nB=blockIdx>>7).
// LDS: As 16KB (64 rows x 128 k) | Bs 32KB (128 rows x 128 k), 48KB total ->
// 3 blocks/CU. 2-barrier K-loop, 8 iterations. XOR swizzle: granule gp (0..15)
// holds global granule gp^(row&7); frag read uses gpx = gpb^(lane&7); rows
// 0..7 cover 8 distinct slots, rows 8..15 alias 2-way (free per m136).
__global__ __launch_bounds__(256) void kb_gemm_measure(
    const f16* __restrict__ psi0, const f16* __restrict__ Arm,
    float* __restrict__ z)
{
    __shared__ __align__(16) char smem[49152];
    const int tid = threadIdx.x, lane = tid & 63, wv = tid >> 6;
    const int mB = blockIdx.x & 127, nB = blockIdx.x >> 7;
    const size_t tM = (size_t)mB * 64, tN = (size_t)nB * 128;
    f16* As = (f16*)smem;                  // 64 x 128
    f16* Bs = (f16*)(smem + 16384);        // 128 x 128
    const int wm = (wv >> 1) * 32, wn = (wv & 1) * 64;

    f32x4 acc[2][4] = {};

    // staging: A 1024 slots (4/thread), B 2048 slots (8/thread); 16 granules/row
    const f16* ga[4]; int ldsoA[4];
    #pragma unroll
    for (int p = 0; p < 4; ++p) {
        int s = p * 256 + tid;
        int row = s >> 4, gp = s & 15, g = gp ^ (row & 7);
        ga[p] = psi0 + (tM + row) * 1024 + g * 8;
        ldsoA[p] = s * 16;  // byte offset within As
    }
    const f16* gb[8]; int ldsoB[8];
    #pragma unroll
    for (int p = 0; p < 8; ++p) {
        int s = p * 256 + tid;
        int row = s >> 4, gp = s & 15, g = gp ^ (row & 7);
        gb[p] = Arm + (tN + row) * 1024 + g * 8;
        ldsoB[p] = 16384 + s * 16;  // byte offset (Bs base)
    }

    for (int kt = 0; kt < 1024; kt += 128) {
        __syncthreads();  // protect LDS reuse from previous iter's reads
        #pragma unroll
        for (int p = 0; p < 4; ++p) async16(ga[p] + kt, smem + ldsoA[p]);
        #pragma unroll
        for (int p = 0; p < 8; ++p) async16(gb[p] + kt, smem + ldsoB[p]);
        __syncthreads();  // staging complete
        #pragma unroll
        for (int ks = 0; ks < 4; ++ks) {
            f16x8 af[2], bf[4];
            const int gpb = ks * 4 + (lane >> 4);   // 0..15
            const int gpx = gpb ^ (lane & 7);
            #pragma unroll
            for (int i = 0; i < 2; ++i) {
                int rowA = wm + i * 16 + (lane & 15);
                af[i] = *(const f16x8*)(As + rowA * 128 + gpx * 8);
            }
            #pragma unroll
            for (int j = 0; j < 4; ++j) {
                int rowB = wn + j * 16 + (lane & 15);
                bf[j] = *(const f16x8*)(Bs + rowB * 128 + gpx * 8);
            }
            #pragma unroll
            for (int i = 0; i < 2; ++i)
                #pragma unroll
                for (int j = 0; j < 4; ++j)
                    acc[i][j] = __builtin_amdgcn_mfma_f32_16x16x32_f16(af[i], bf[j], acc[i][j], 0, 0, 0);
        }
    }

    // ---- fused +-square measurement epilogue (R6-verified 64x128 mapping) ----
    __syncthreads();  // done with As/Bs; reuse as zbuf[2][64][10] f32
    float* zbuf = (float*)smem;
    float* zb = zbuf + (wn ? 640 : 0);
    const float sg0 = (nB & 4) ? -1.0f : 1.0f;  // wire0 <- n[9]
    const float sg1 = (nB & 2) ? -1.0f : 1.0f;  // wire1 <- n[8]
    const float sg2 = (nB & 1) ? -1.0f : 1.0f;  // wire2 <- n[7]
    const float sg3 = wn ? -1.0f : 1.0f;        // wire3 <- n[6]

    #pragma unroll
    for (int i = 0; i < 2; ++i) {
        #pragma unroll
        for (int t = 0; t < 4; ++t) {
            float p0 = acc[i][0][t] * acc[i][0][t];
            float p1 = acc[i][1][t] * acc[i][1][t];
            float p2 = acc[i][2][t] * acc[i][2][t];
            float p3 = acc[i][3][t] * acc[i][3][t];
            float t0  = (p0 + p1) + (p2 + p3);
            float tw5 = (p0 - p1) + (p2 - p3);  // wire5 <- n[4] = j&1
            float tw4 = (p0 + p1) - (p2 + p3);  // wire4 <- n[5] = j>>1
            // butterfly over lane bits 0..3 = n[0..3] -> wires 9,8,7,6
            float s1 = __shfl_xor(t0, 1);
            float Av = t0 + s1;
            float Bv = (lane & 1) ? s1 - t0 : t0 - s1;
            float sA = __shfl_xor(Av, 2), sB = __shfl_xor(Bv, 2);
            float AP = Av + sA;
            float AM = (lane & 2) ? sA - Av : Av - sA;
            float BP = Bv + sB;
            float sAP = __shfl_xor(AP, 4), sAM = __shfl_xor(AM, 4), sBP = __shfl_xor(BP, 4);
            float APP = AP + sAP;
            float APM = (lane & 4) ? sAP - AP : AP - sAP;
            float AMP = AM + sAM;
            float BPP = BP + sBP;
            float a1 = __shfl_xor(APP, 8), a2 = __shfl_xor(APM, 8);
            float a3 = __shfl_xor(AMP, 8), a4 = __shfl_xor(BPP, 8);
            float T0 = APP + a1;
            float S6 = (lane & 8) ? a1 - APP : APP - a1;
            float S7 = APM + a2;
            float S8 = AMP + a3;
            float S9 = BPP + a4;
            float T5 = tw5, T4 = tw4;
            T5 += __shfl_xor(T5, 1); T5 += __shfl_xor(T5, 2);
            T5 += __shfl_xor(T5, 4); T5 += __shfl_xor(T5, 8);
            T4 += __shfl_xor(T4, 1); T4 += __shfl_xor(T4, 2);
            T4 += __shfl_xor(T4, 4); T4 += __shfl_xor(T4, 8);
            if ((lane & 15) == 0) {
                int row = wm + i * 16 + (lane >> 4) * 4 + t;
                float* d = zb + row * 10;
                d[0] = sg0 * T0; d[1] = sg1 * T0; d[2] = sg2 * T0; d[3] = sg3 * T0;
                d[4] = T4; d[5] = T5;
                d[6] = S6; d[7] = S7; d[8] = S8; d[9] = S9;
            }
        }
    }
    __syncthreads();
    // combine col-halves, atomic-accumulate into z[tM+row][10]
    for (int idx = tid; idx < 640; idx += 256) {
        float v = zbuf[idx] + zbuf[640 + idx];
        int row = idx / 10, w = idx - row * 10;
        atomicAdd(&z[((size_t)tM + row) * 10 + w], v);
    }
}

// ---------------------------------------------------------------- KC  [R6-verified]
__global__ __launch_bounds__(256) void kc_post(
    const float* __restrict__ z, const float* __restrict__ Wpost,
    const float* __restrict__ bpost, float* __restrict__ out, int B)
{
    int gid = blockIdx.x * 256 + threadIdx.x;
    if (gid >= B) return;
    const float* zp = z + (size_t)gid * NQ;
    float o0 = bpost[0], o1 = bpost[1];
    #pragma unroll
    for (int w = 0; w < NQ; ++w) {
        float zw = zp[w];
        o0 = fmaf(zw, Wpost[w], o0);
        o1 = fmaf(zw, Wpost[NQ + w], o1);
    }
    out[(size_t)gid * 2 + 0] = o0;
    out[(size_t)gid * 2 + 1] = o1;
}

// ---------------------------------------------------------------- fallback (R1, verified)
template<int BC, int BT>
__device__ __forceinline__ void cnot_lane(float (&s)[NREG], int lane) {
    int src = ((lane >> BC) & 1) ? (lane ^ (1 << BT)) : lane;
    #pragma unroll
    for (int r = 0; r < NREG; ++r) s[r] = __shfl(s[r], src);
}

__global__ __launch_bounds__(256) void hybrid_head_fallback(
    const float* __restrict__ X, const float* __restrict__ Wpre,
    const float* __restrict__ bpre, const float* __restrict__ qp,
    const float* __restrict__ Wpost, const float* __restrict__ bpost,
    float* __restrict__ out, int B)
{
    const int lane = threadIdx.x & 63;
    const int wave = threadIdx.x >> 6;
    const int sample = blockIdx.x * 4 + wave;
    if (sample >= B) return;

    const float* xrow = X + (size_t)sample * 512;
    float4 x0 = ((const float4*)xrow)[lane];
    float4 x1 = ((const float4*)xrow)[64 + lane];
    float acc[NQ];
    #pragma unroll
    for (int q = 0; q < NQ; ++q) {
        const float* wr = Wpre + q * 512;
        float4 w0 = ((const float4*)wr)[lane];
        float4 w1 = ((const float4*)wr)[64 + lane];
        float a = x0.x * w0.x;
        a = fmaf(x0.y, w0.y, a); a = fmaf(x0.z, w0.z, a); a = fmaf(x0.w, w0.w, a);
        a = fmaf(x1.x, w1.x, a); a = fmaf(x1.y, w1.y, a);
        a = fmaf(x1.z, w1.z, a); a = fmaf(x1.w, w1.w, a);
        acc[q] = a;
    }
    #pragma unroll
    for (int q = 0; q < NQ; ++q) {
        float v = acc[q];
        #pragma unroll
        for (int d = 32; d >= 1; d >>= 1) v += __shfl_xor(v, d);
        acc[q] = v;
    }
    float pre = acc[0];
    #pragma unroll
    for (int q = 1; q < NQ; ++q) pre = (lane == q) ? acc[q] : pre;
    float cth = 1.0f, sth = 0.0f;
    if (lane < NQ) {
        float th = tanhf(pre + bpre[lane]) * 1.5707963267948966f;
        sincosf(0.5f * th, &sth, &cth);
    }
    float cw = 1.0f, sw = 0.0f;
    if (lane < 60) sincosf(0.5f * qp[10 + lane], &sw, &cw);

    float s[NREG];
    #pragma unroll
    for (int r = 0; r < NREG; ++r) s[r] = 0.03125f;
    APPLY_RY_ALL(cth, sth, 0);
    for (int k = 0; k < 6; ++k) {
        perm_even(s, lane);
        cnot_reg<3, 2>(s);
        cnot_reg<1, 0>(s);
        perm_odd(s, lane);
        cnot_5_6(s, lane);
        cnot_reg<2, 1>(s);
        APPLY_RY_ALL(cw, sw, k * 10);
    }
    float p[NREG], tot = 0.0f;
    #pragma unroll
    for (int r = 0; r < NREG; ++r) { p[r] = s[r] * s[r]; tot += p[r]; }
    float z[NQ];
    #pragma unroll
    for (int w = 0; w < 6; ++w) z[w] = ((lane >> (5 - w)) & 1) ? -tot : tot;
    z[6] = z[7] = z[8] = z[9] = 0.0f;
    #pragma unroll
    for (int r = 0; r < NREG; ++r) {
        z[6] += ((r >> 3) & 1) ? -p[r] : p[r];
        z[7] += ((r >> 2) & 1) ? -p[r] : p[r];
        z[8] += ((r >> 1) & 1) ? -p[r] : p[r];
        z[9] += ((r >> 0) & 1) ? -p[r] : p[r];
    }
    #pragma unroll
    for (int w = 0; w < NQ; ++w) {
        float v = z[w];
        #pragma unroll
        for (int d = 32; d >= 1; d >>= 1) v += __shfl_xor(v, d);
        z[w] = v;
    }
    if (lane < 2) {
        const float* wp = Wpost + lane * NQ;
        float o = bpost[lane];
        #pragma unroll
        for (int w = 0; w < NQ; ++w) o = fmaf(z[w], wp[w], o);
        out[(size_t)sample * 2 + lane] = o;
    }
}

// ---------------------------------------------------------------- launch
extern "C" void kernel_launch(void* const* d_in, const int* in_sizes, int n_in,
                              void* d_out, int out_size, void* d_ws, size_t ws_size,
                              hipStream_t stream) {
    const float* X     = (const float*)d_in[0];
    const float* Wpre  = (const float*)d_in[1];
    const float* bpre  = (const float*)d_in[2];
    const float* qp    = (const float*)d_in[3];
    const float* Wpost = (const float*)d_in[4];
    const float* bpost = (const float*)d_in[5];
    float* out = (float*)d_out;
    int B = in_sizes[0] / 512;  // 8192

    size_t psi0_b = (size_t)B * DIM * sizeof(f16);      // 16 MB
    size_t arm_b  = (size_t)DIM * DIM * sizeof(f16);    // 2 MB
    size_t z_b    = (size_t)B * NQ * sizeof(float);     // 320 KB
    size_t need = psi0_b + arm_b + z_b;

    if (B != 8192 || ws_size < need) {
        hipLaunchKernelGGL(hybrid_head_fallback, dim3((B + 3) / 4), dim3(256), 0, stream,
                           X, Wpre, bpre, qp, Wpost, bpost, out, B);
        return;
    }

    char* ws = (char*)d_ws;
    f16*   psi0 = (f16*)ws;
    f16*   Arm  = (f16*)(ws + psi0_b);
    float* z    = (float*)(ws + psi0_b + arm_b);

    hipLaunchKernelGGL(ka_prepare, dim3(2048), dim3(256), 0, stream,
                       X, Wpre, bpre, qp, psi0, Arm, z, B);
    hipLaunchKernelGGL(kb_gemm_measure, dim3(1024), dim3(256), 0, stream,
                       psi0, Arm, z);
    hipLaunchKernelGGL(kc_post, dim3(32), dim3(256), 0, stream,
                       z, Wpost, bpost, out, B);
}

// Round 13
// 119.278 us; speedup vs baseline: 1.0318x; 1.0318x over previous
//
#include <hip/hip_runtime.h>
#include <math.h>

// BaseHybridHead, 3 stream-ordered kernels (R11 = best-known; KA de-straggled):
//  KA: grid 2304. Blocks 0..2047: zero z + psi0 (1 sample/wave).
//      Blocks 2048..2303: Arm rows only (4 waves x 1 row) -- the ~800-op
//      dependent gate chain now runs CONCURRENT with psi0 blocks instead of
//      serially after a sample in the same wave (R11's straggler tail).
//  KB: MFMA GEMM psif = psi0 @ Arm^T, 128x128 tile, BK=64, XOR-swizzled LDS,
//      2-barrier staged K-loop, 512 blocks. Fused +-square measurement
//      epilogue -> LDS combine -> atomicAdd z.      [R11-verified, unchanged]
//  KC: out = z @ Wpost^T + bpost.                   [R6-verified, unchanged]

#define NQ   10
#define NREG 16
#define DIM  1024

typedef _Float16 f16;
typedef _Float16 f16x8 __attribute__((ext_vector_type(8)));
typedef float    f32x4 __attribute__((ext_vector_type(4)));

// ---------------------------------------------------------------- gate ops
template<int BB>
__device__ __forceinline__ void ry_lane(float (&s)[NREG], int lane, float c, float si) {
    float sgn = ((lane >> BB) & 1) ? si : -si;
    #pragma unroll
    for (int r = 0; r < NREG; ++r) {
        float o = __shfl_xor(s[r], 1 << BB);
        s[r] = fmaf(sgn, o, c * s[r]);
    }
}
template<int P>
__device__ __forceinline__ void ry_reg(float (&s)[NREG], float c, float si) {
    const int m = 1 << P;
    #pragma unroll
    for (int r = 0; r < NREG; ++r) {
        if ((r & m) == 0) {
            float a = s[r], b = s[r + m];
            s[r]     = fmaf(c, a, -si * b);
            s[r + m] = fmaf(si, a,  c * b);
        }
    }
}
__device__ __forceinline__ void cnot_5_6(float (&s)[NREG], int lane) {
    bool sel = (lane & 1) != 0;
    #pragma unroll
    for (int r = 0; r < 8; ++r) {
        float a = s[r], b = s[r + 8];
        s[r]     = sel ? b : a;
        s[r + 8] = sel ? a : b;
    }
}
template<int PC, int PT>
__device__ __forceinline__ void cnot_reg(float (&s)[NREG]) {
    #pragma unroll
    for (int r = 0; r < NREG; ++r) {
        if (((r >> PC) & 1) && !((r >> PT) & 1)) {
            float t = s[r];
            s[r] = s[r ^ (1 << PT)];
            s[r ^ (1 << PT)] = t;
        }
    }
}
__device__ __forceinline__ void perm_even(float (&s)[NREG], int lane) {
    int src = lane ^ (((((lane >> 5) & 1) << 4)) | ((((lane >> 3) & 1) << 2)) | (((lane >> 1) & 1)));
    #pragma unroll
    for (int r = 0; r < NREG; ++r) s[r] = __shfl(s[r], src);
}
__device__ __forceinline__ void perm_odd(float (&s)[NREG], int lane) {
    int src = lane ^ (((((lane >> 4) & 1) << 3)) | ((((lane >> 2) & 1) << 1)));
    #pragma unroll
    for (int r = 0; r < NREG; ++r) s[r] = __shfl(s[r], src);
}

#define APPLY_RY_ALL(CARR, SARR, BASE)                                        \
    { float c_, s_;                                                           \
      c_=__shfl(CARR,(BASE)+0); s_=__shfl(SARR,(BASE)+0); ry_lane<5>(s,lane,c_,s_); \
      c_=__shfl(CARR,(BASE)+1); s_=__shfl(SARR,(BASE)+1); ry_lane<4>(s,lane,c_,s_); \
      c_=__shfl(CARR,(BASE)+2); s_=__shfl(SARR,(BASE)+2); ry_lane<3>(s,lane,c_,s_); \
      c_=__shfl(CARR,(BASE)+3); s_=__shfl(SARR,(BASE)+3); ry_lane<2>(s,lane,c_,s_); \
      c_=__shfl(CARR,(BASE)+4); s_=__shfl(SARR,(BASE)+4); ry_lane<1>(s,lane,c_,s_); \
      c_=__shfl(CARR,(BASE)+5); s_=__shfl(SARR,(BASE)+5); ry_lane<0>(s,lane,c_,s_); \
      c_=__shfl(CARR,(BASE)+6); s_=__shfl(SARR,(BASE)+6); ry_reg<3>(s,c_,s_);       \
      c_=__shfl(CARR,(BASE)+7); s_=__shfl(SARR,(BASE)+7); ry_reg<2>(s,c_,s_);       \
      c_=__shfl(CARR,(BASE)+8); s_=__shfl(SARR,(BASE)+8); ry_reg<1>(s,c_,s_);       \
      c_=__shfl(CARR,(BASE)+9); s_=__shfl(SARR,(BASE)+9); ry_reg<0>(s,c_,s_); }

__device__ __forceinline__ void async16(const void* g, void* l) {
    __builtin_amdgcn_global_load_lds(
        (const __attribute__((address_space(1))) void*)g,
        (__attribute__((address_space(3))) void*)l, 16, 0, 0);
}

// ---------------------------------------------------------------- KA
// grid 2304: blocks 0..2047 psi0 (+ zero z); blocks 2048..2303 Arm rows.
__global__ __launch_bounds__(256) void ka_prepare(
    const float* __restrict__ X, const float* __restrict__ Wpre,
    const float* __restrict__ bpre, const float* __restrict__ qp,
    f16* __restrict__ psi0, f16* __restrict__ Arm, float* __restrict__ z, int B)
{
    const int tid = threadIdx.x, lane = tid & 63, wv = tid >> 6;

    if (blockIdx.x < 2048) {
        // ---- zero z accumulator (81920 floats; first 320 blocks cover it)
        int idx = blockIdx.x * 256 + tid;
        if (idx < 8192 * NQ) z[idx] = 0.0f;

        // ---- psi0: one sample per wave  [R7/R11-verified]
        int sample = blockIdx.x * 4 + wv;
        if (sample < B) {
            const float* xrow = X + (size_t)sample * 512;
            float4 x0 = ((const float4*)xrow)[lane];
            float4 x1 = ((const float4*)xrow)[64 + lane];
            float acc[NQ];
            #pragma unroll
            for (int q = 0; q < NQ; ++q) {
                const float* wr = Wpre + q * 512;
                float4 w0 = ((const float4*)wr)[lane];
                float4 w1 = ((const float4*)wr)[64 + lane];
                float a = x0.x * w0.x;
                a = fmaf(x0.y, w0.y, a); a = fmaf(x0.z, w0.z, a); a = fmaf(x0.w, w0.w, a);
                a = fmaf(x1.x, w1.x, a); a = fmaf(x1.y, w1.y, a);
                a = fmaf(x1.z, w1.z, a); a = fmaf(x1.w, w1.w, a);
                acc[q] = a;
            }
            #pragma unroll
            for (int q = 0; q < NQ; ++q) {
                float v = acc[q];
                #pragma unroll
                for (int d = 32; d >= 1; d >>= 1) v += __shfl_xor(v, d);
                acc[q] = v;
            }
            float pre = acc[0];
            #pragma unroll
            for (int q = 1; q < NQ; ++q) pre = (lane == q) ? acc[q] : pre;
            float c45 = 0.0f, s45 = 0.0f;
            if (lane < NQ) {
                float th = tanhf(pre + bpre[lane]) * 1.5707963267948966f;
                sincosf(0.5f * th + 0.7853981633974483f, &s45, &c45);
            }
            float lv = 1.0f;
            #pragma unroll
            for (int w = 0; w < 6; ++w) {
                float f0 = __shfl(c45, w), f1 = __shfl(s45, w);
                lv *= ((lane >> (5 - w)) & 1) ? f1 : f0;
            }
            float c6 = __shfl(c45, 6), s6 = __shfl(s45, 6);
            float c7 = __shfl(c45, 7), s7 = __shfl(s45, 7);
            float c8 = __shfl(c45, 8), s8 = __shfl(s45, 8);
            float c9 = __shfl(c45, 9), s9 = __shfl(s45, 9);
            float g01[4] = {c6 * c7, c6 * s7, s6 * c7, s6 * s7};
            float g23[4] = {c8 * c9, c8 * s9, s8 * c9, s8 * s9};
            union { f16 h[16]; float4 v[2]; } u;
            #pragma unroll
            for (int r = 0; r < NREG; ++r)
                u.h[r] = (f16)(lv * g01[r >> 2] * g23[r & 3]);
            float4* dst = (float4*)((char*)psi0 + (size_t)sample * 2048 + lane * 32);
            dst[0] = u.v[0];
            dst[1] = u.v[1];
        }
    } else {
        // ---- Arm rows: 256 blocks x 4 waves x 1 row  [chain verified R9/R11]
        int row = (blockIdx.x - 2048) * 4 + wv;
        if (row < DIM) {
            float cw = 1.0f, swn = 0.0f;
            if (lane < 60) {
                float s_, c_;
                sincosf(0.5f * qp[10 + lane], &s_, &c_);
                cw = c_; swn = -s_;
            }
            float s[NREG];
            int srcLane = row >> 4, srcReg = row & 15;
            #pragma unroll
            for (int r = 0; r < NREG; ++r)
                s[r] = (lane == srcLane && r == srcReg) ? 1.0f : 0.0f;
            for (int kk = 6; kk >= 1; --kk) {
                APPLY_RY_ALL(cw, swn, (kk - 1) * 10);
                perm_odd(s, lane);
                cnot_5_6(s, lane);
                cnot_reg<2, 1>(s);
                perm_even(s, lane);
                cnot_reg<3, 2>(s);
                cnot_reg<1, 0>(s);
            }
            union { f16 h[16]; float4 v[2]; } u;
            #pragma unroll
            for (int r = 0; r < NREG; ++r) u.h[r] = (f16)s[r];
            float4* dst = (float4*)((char*)Arm + (size_t)row * 2048 + lane * 32);
            dst[0] = u.v[0];
            dst[1] = u.v[1];
        }
    }
}

// ---------------------------------------------------------------- KB  [R11-verified, unchanged]
__global__ __launch_bounds__(256) void kb_gemm_measure(
    const f16* __restrict__ psi0, const f16* __restrict__ Arm,
    float* __restrict__ z)
{
    __shared__ __align__(16) char smem[32768];  // As 16K | Bs 16K ; reused as zbuf
    const int tid = threadIdx.x, lane = tid & 63, wv = tid >> 6;
    const int mB = blockIdx.x & 63, nB = blockIdx.x >> 6;
    const size_t tM = (size_t)mB * 128, tN = (size_t)nB * 128;
    f16* As = (f16*)smem;
    f16* Bs = (f16*)(smem + 16384);
    const int wm = (wv >> 1) * 64, wn = (wv & 1) * 64;

    f32x4 acc[4][4] = {};

    const f16* ga[4]; const f16* gb[4]; int ldso[4];
    #pragma unroll
    for (int p = 0; p < 4; ++p) {
        int slot = p * 256 + tid;
        int row = slot >> 3, gp = slot & 7, g = gp ^ (row & 7);
        ga[p] = psi0 + (tM + row) * 1024 + g * 8;
        gb[p] = Arm  + (tN + row) * 1024 + g * 8;
        ldso[p] = slot * 16;
    }

    for (int kt = 0; kt < 1024; kt += 64) {
        __syncthreads();
        #pragma unroll
        for (int p = 0; p < 4; ++p) async16(ga[p] + kt, (char*)As + ldso[p]);
        #pragma unroll
        for (int p = 0; p < 4; ++p) async16(gb[p] + kt, (char*)Bs + ldso[p]);
        __syncthreads();
        #pragma unroll
        for (int ks = 0; ks < 2; ++ks) {
            f16x8 af[4], bf[4];
            const int gpb = ks * 4 + (lane >> 4);
            const int gpx = gpb ^ (lane & 7);
            #pragma unroll
            for (int i = 0; i < 4; ++i) {
                int rowA = wm + i * 16 + (lane & 15);
                af[i] = *(const f16x8*)(As + rowA * 64 + gpx * 8);
            }
            #pragma unroll
            for (int j = 0; j < 4; ++j) {
                int rowB = wn + j * 16 + (lane & 15);
                bf[j] = *(const f16x8*)(Bs + rowB * 64 + gpx * 8);
            }
            #pragma unroll
            for (int i = 0; i < 4; ++i)
                #pragma unroll
                for (int j = 0; j < 4; ++j)
                    acc[i][j] = __builtin_amdgcn_mfma_f32_16x16x32_f16(af[i], bf[j], acc[i][j], 0, 0, 0);
        }
    }

    __syncthreads();  // done with As/Bs; reuse as zbuf[2][128][10] f32
    float* zbuf = (float*)smem;
    float* zb = zbuf + (wn ? 1280 : 0);
    const float sg0 = (nB & 4) ? -1.0f : 1.0f;  // wire0 <- n[9]
    const float sg1 = (nB & 2) ? -1.0f : 1.0f;  // wire1 <- n[8]
    const float sg2 = (nB & 1) ? -1.0f : 1.0f;  // wire2 <- n[7]
    const float sg3 = wn ? -1.0f : 1.0f;        // wire3 <- n[6]

    #pragma unroll
    for (int i = 0; i < 4; ++i) {
        #pragma unroll
        for (int t = 0; t < 4; ++t) {
            float p0 = acc[i][0][t] * acc[i][0][t];
            float p1 = acc[i][1][t] * acc[i][1][t];
            float p2 = acc[i][2][t] * acc[i][2][t];
            float p3 = acc[i][3][t] * acc[i][3][t];
            float t0  = (p0 + p1) + (p2 + p3);
            float tw5 = (p0 - p1) + (p2 - p3);  // wire5 <- n[4] = j&1
            float tw4 = (p0 + p1) - (p2 + p3);  // wire4 <- n[5] = j>>1
            float s1 = __shfl_xor(t0, 1);
            float Av = t0 + s1;
            float Bv = (lane & 1) ? s1 - t0 : t0 - s1;
            float sA = __shfl_xor(Av, 2), sB = __shfl_xor(Bv, 2);
            float AP = Av + sA;
            float AM = (lane & 2) ? sA - Av : Av - sA;
            float BP = Bv + sB;
            float sAP = __shfl_xor(AP, 4), sAM = __shfl_xor(AM, 4), sBP = __shfl_xor(BP, 4);
            float APP = AP + sAP;
            float APM = (lane & 4) ? sAP - AP : AP - sAP;
            float AMP = AM + sAM;
            float BPP = BP + sBP;
            float a1 = __shfl_xor(APP, 8), a2 = __shfl_xor(APM, 8);
            float a3 = __shfl_xor(AMP, 8), a4 = __shfl_xor(BPP, 8);
            float T0 = APP + a1;
            float S6 = (lane & 8) ? a1 - APP : APP - a1;
            float S7 = APM + a2;
            float S8 = AMP + a3;
            float S9 = BPP + a4;
            float T5 = tw5, T4 = tw4;
            T5 += __shfl_xor(T5, 1); T5 += __shfl_xor(T5, 2);
            T5 += __shfl_xor(T5, 4); T5 += __shfl_xor(T5, 8);
            T4 += __shfl_xor(T4, 1); T4 += __shfl_xor(T4, 2);
            T4 += __shfl_xor(T4, 4); T4 += __shfl_xor(T4, 8);
            if ((lane & 15) == 0) {
                int row = wm + i * 16 + (lane >> 4) * 4 + t;
                float* d = zb + row * 10;
                d[0] = sg0 * T0; d[1] = sg1 * T0; d[2] = sg2 * T0; d[3] = sg3 * T0;
                d[4] = T4; d[5] = T5;
                d[6] = S6; d[7] = S7; d[8] = S8; d[9] = S9;
            }
        }
    }
    __syncthreads();
    for (int idx = tid; idx < 1280; idx += 256) {
        float v = zbuf[idx] + zbuf[1280 + idx];
        int row = idx / 10, w = idx - row * 10;
        atomicAdd(&z[((size_t)tM + row) * 10 + w], v);
    }
}

// ---------------------------------------------------------------- KC  [R6-verified]
__global__ __launch_bounds__(256) void kc_post(
    const float* __restrict__ z, const float* __restrict__ Wpost,
    const float* __restrict__ bpost, float* __restrict__ out, int B)
{
    int gid = blockIdx.x * 256 + threadIdx.x;
    if (gid >= B) return;
    const float* zp = z + (size_t)gid * NQ;
    float o0 = bpost[0], o1 = bpost[1];
    #pragma unroll
    for (int w = 0; w < NQ; ++w) {
        float zw = zp[w];
        o0 = fmaf(zw, Wpost[w], o0);
        o1 = fmaf(zw, Wpost[NQ + w], o1);
    }
    out[(size_t)gid * 2 + 0] = o0;
    out[(size_t)gid * 2 + 1] = o1;
}

// ---------------------------------------------------------------- fallback (R1, verified)
template<int BC, int BT>
__device__ __forceinline__ void cnot_lane(float (&s)[NREG], int lane) {
    int src = ((lane >> BC) & 1) ? (lane ^ (1 << BT)) : lane;
    #pragma unroll
    for (int r = 0; r < NREG; ++r) s[r] = __shfl(s[r], src);
}

__global__ __launch_bounds__(256) void hybrid_head_fallback(
    const float* __restrict__ X, const float* __restrict__ Wpre,
    const float* __restrict__ bpre, const float* __restrict__ qp,
    const float* __restrict__ Wpost, const float* __restrict__ bpost,
    float* __restrict__ out, int B)
{
    const int lane = threadIdx.x & 63;
    const int wave = threadIdx.x >> 6;
    const int sample = blockIdx.x * 4 + wave;
    if (sample >= B) return;

    const float* xrow = X + (size_t)sample * 512;
    float4 x0 = ((const float4*)xrow)[lane];
    float4 x1 = ((const float4*)xrow)[64 + lane];
    float acc[NQ];
    #pragma unroll
    for (int q = 0; q < NQ; ++q) {
        const float* wr = Wpre + q * 512;
        float4 w0 = ((const float4*)wr)[lane];
        float4 w1 = ((const float4*)wr)[64 + lane];
        float a = x0.x * w0.x;
        a = fmaf(x0.y, w0.y, a); a = fmaf(x0.z, w0.z, a); a = fmaf(x0.w, w0.w, a);
        a = fmaf(x1.x, w1.x, a); a = fmaf(x1.y, w1.y, a);
        a = fmaf(x1.z, w1.z, a); a = fmaf(x1.w, w1.w, a);
        acc[q] = a;
    }
    #pragma unroll
    for (int q = 0; q < NQ; ++q) {
        float v = acc[q];
        #pragma unroll
        for (int d = 32; d >= 1; d >>= 1) v += __shfl_xor(v, d);
        acc[q] = v;
    }
    float pre = acc[0];
    #pragma unroll
    for (int q = 1; q < NQ; ++q) pre = (lane == q) ? acc[q] : pre;
    float cth = 1.0f, sth = 0.0f;
    if (lane < NQ) {
        float th = tanhf(pre + bpre[lane]) * 1.5707963267948966f;
        sincosf(0.5f * th, &sth, &cth);
    }
    float cw = 1.0f, sw = 0.0f;
    if (lane < 60) sincosf(0.5f * qp[10 + lane], &sw, &cw);

    float s[NREG];
    #pragma unroll
    for (int r = 0; r < NREG; ++r) s[r] = 0.03125f;
    APPLY_RY_ALL(cth, sth, 0);
    for (int k = 0; k < 6; ++k) {
        perm_even(s, lane);
        cnot_reg<3, 2>(s);
        cnot_reg<1, 0>(s);
        perm_odd(s, lane);
        cnot_5_6(s, lane);
        cnot_reg<2, 1>(s);
        APPLY_RY_ALL(cw, sw, k * 10);
    }
    float p[NREG], tot = 0.0f;
    #pragma unroll
    for (int r = 0; r < NREG; ++r) { p[r] = s[r] * s[r]; tot += p[r]; }
    float z[NQ];
    #pragma unroll
    for (int w = 0; w < 6; ++w) z[w] = ((lane >> (5 - w)) & 1) ? -tot : tot;
    z[6] = z[7] = z[8] = z[9] = 0.0f;
    #pragma unroll
    for (int r = 0; r < NREG; ++r) {
        z[6] += ((r >> 3) & 1) ? -p[r] : p[r];
        z[7] += ((r >> 2) & 1) ? -p[r] : p[r];
        z[8] += ((r >> 1) & 1) ? -p[r] : p[r];
        z[9] += ((r >> 0) & 1) ? -p[r] : p[r];
    }
    #pragma unroll
    for (int w = 0; w < NQ; ++w) {
        float v = z[w];
        #pragma unroll
        for (int d = 32; d >= 1; d >>= 1) v += __shfl_xor(v, d);
        z[w] = v;
    }
    if (lane < 2) {
        const float* wp = Wpost + lane * NQ;
        float o = bpost[lane];
        #pragma unroll
        for (int w = 0; w < NQ; ++w) o = fmaf(z[w], wp[w], o);
        out[(size_t)sample * 2 + lane] = o;
    }
}

// ---------------------------------------------------------------- launch
extern "C" void kernel_launch(void* const* d_in, const int* in_sizes, int n_in,
                              void* d_out, int out_size, void* d_ws, size_t ws_size,
                              hipStream_t stream) {
    const float* X     = (const float*)d_in[0];
    const float* Wpre  = (const float*)d_in[1];
    const float* bpre  = (const float*)d_in[2];
    const float* qp    = (const float*)d_in[3];
    const float* Wpost = (const float*)d_in[4];
    const float* bpost = (const float*)d_in[5];
    float* out = (float*)d_out;
    int B = in_sizes[0] / 512;  // 8192

    size_t psi0_b = (size_t)B * DIM * sizeof(f16);      // 16 MB
    size_t arm_b  = (size_t)DIM * DIM * sizeof(f16);    // 2 MB
    size_t z_b    = (size_t)B * NQ * sizeof(float);     // 320 KB
    size_t need = psi0_b + arm_b + z_b;

    if (B != 8192 || ws_size < need) {
        hipLaunchKernelGGL(hybrid_head_fallback, dim3((B + 3) / 4), dim3(256), 0, stream,
                           X, Wpre, bpre, qp, Wpost, bpost, out, B);
        return;
    }

    char* ws = (char*)d_ws;
    f16*   psi0 = (f16*)ws;
    f16*   Arm  = (f16*)(ws + psi0_b);
    float* z    = (float*)(ws + psi0_b + arm_b);

    hipLaunchKernelGGL(ka_prepare, dim3(2304), dim3(256), 0, stream,
                       X, Wpre, bpre, qp, psi0, Arm, z, B);
    hipLaunchKernelGGL(kb_gemm_measure, dim3(512), dim3(256), 0, stream,
                       psi0, Arm, z);
    hipLaunchKernelGGL(kc_post, dim3(32), dim3(256), 0, stream,
                       z, Wpost, bpost, out, B);
}